// Round 1
// baseline (206.880 us; speedup 1.0000x reference)
//
#include <hip/hip_runtime.h>
#include <math.h>

namespace {
constexpr int NB = 2048;      // batch
constexpr int NNODE = 6;      // nodes
constexpr int DD = 2048;      // feature dim
constexpr int HH = 1024;      // hidden
constexpr int CC = 200;       // classes
constexpr int K2 = 2 * DD;    // 4096 (concat dim)
constexpr float ALPHA_C = 0.015f;
constexpr float SCALE_C = 24.0f;
constexpr int SPLITK = 4;
}

// ---------------------------------------------------------------------------
// s[b][u] = (SCALE/(N-1)) * sum_v max(w0[u,v]-mean_w, 0) (off-diagonal)
// ---------------------------------------------------------------------------
__global__ __launch_bounds__(256) void k_s(const float* __restrict__ cdds,
                                           float* __restrict__ s)
{
    int b = blockIdx.x * blockDim.x + threadIdx.x;
    if (b >= NB) return;
    const float* cd = cdds + (size_t)b * NNODE * 6;
    float cx[NNODE], cy[NNODE];
#pragma unroll
    for (int u = 0; u < NNODE; ++u) {
        // loc = cdds[...,1:5]; cy=(loc0+loc2)/2, cx=(loc1+loc3)/2
        cy[u] = (cd[u * 6 + 1] + cd[u * 6 + 3]) * 0.5f;
        cx[u] = (cd[u * 6 + 2] + cd[u * 6 + 4]) * 0.5f;
    }
    float w0[NNODE][NNODE];
    float sum = 0.f;
#pragma unroll
    for (int u = 0; u < NNODE; ++u) {
#pragma unroll
        for (int v = 0; v < NNODE; ++v) {
            if (v == u) { w0[u][v] = 0.f; continue; }
            float dx = cx[u] - cx[v];
            float dy = cy[u] - cy[v];
            float dist = sqrtf(dx * dx + dy * dy);
            float w = expf(-ALPHA_C * dist);
            w0[u][v] = w;
            sum += w;
        }
    }
    float mean = sum * (1.f / 30.f);   // N*(N-1) = 30
#pragma unroll
    for (int u = 0; u < NNODE; ++u) {
        float acc = 0.f;
#pragma unroll
        for (int v = 0; v < NNODE; ++v) {
            float t = w0[u][v] - mean;
            if (v != u && t > 0.f) acc += t;
        }
        s[b * NNODE + u] = SCALE_C * acc * 0.2f;  // /(N-1)=5
    }
}

// ---------------------------------------------------------------------------
// pq[b][0:D]   = p = sum_u s[b,u]*part_feats[b,u,:]
// pq[b][D:2D]  = q = sum_u part_feats[b,u,:]
// ---------------------------------------------------------------------------
__global__ __launch_bounds__(256) void k_pq(const float* __restrict__ pf,
                                            const float* __restrict__ s,
                                            float* __restrict__ pq)
{
    int idx = blockIdx.x * blockDim.x + threadIdx.x;  // NB * DD/4 threads
    int b = idx >> 9;            // DD/4 = 512
    int d4 = (idx & 511) << 2;
    float sv[NNODE];
#pragma unroll
    for (int u = 0; u < NNODE; ++u) sv[u] = s[b * NNODE + u];
    const float* base = pf + (size_t)b * NNODE * DD + d4;
    float4 p = {0.f, 0.f, 0.f, 0.f};
    float4 q = {0.f, 0.f, 0.f, 0.f};
#pragma unroll
    for (int u = 0; u < NNODE; ++u) {
        float4 a = *(const float4*)(base + (size_t)u * DD);
        p.x = fmaf(sv[u], a.x, p.x); p.y = fmaf(sv[u], a.y, p.y);
        p.z = fmaf(sv[u], a.z, p.z); p.w = fmaf(sv[u], a.w, p.w);
        q.x += a.x; q.y += a.y; q.z += a.z; q.w += a.w;
    }
    float* o = pq + (size_t)b * K2;
    *(float4*)(o + d4) = p;
    *(float4*)(o + DD + d4) = q;
}

// ---------------------------------------------------------------------------
// bvec[c] = sum_h fc_b[h]*cls_w[h,c] + cls_b[c]
// grid: CC/8 = 25 blocks x 256 threads (32 h-slots x 8 c)
// ---------------------------------------------------------------------------
__global__ __launch_bounds__(256) void k_bvec(const float* __restrict__ fc_b,
                                              const float* __restrict__ cls_w,
                                              const float* __restrict__ cls_b,
                                              float* __restrict__ bvec)
{
    __shared__ float red[256];
    int t = threadIdx.x;
    int c8 = t & 7;
    int hs = t >> 3;  // 0..31
    int c = blockIdx.x * 8 + c8;
    float acc = 0.f;
    for (int h = hs; h < HH; h += 32)
        acc += fc_b[h] * cls_w[h * CC + c];
    red[t] = acc;
    __syncthreads();
    for (int sft = 128; sft >= 8; sft >>= 1) {
        if (t < sft) red[t] += red[t + sft];
        __syncthreads();
    }
    if (t < 8) bvec[c] = red[t] + cls_b[c];
}

// ---------------------------------------------------------------------------
// Tiled fp32 GEMM: Cm[z] += A[bm:bm+TM, kbase:kbase+k_len] * B[..., bn:bn+64]
// Block tile TM x 64, 256 threads (16x16), micro (TM/16) x 4, K-step 16.
// Writes RAW partial products (no alpha/bias) at Cm + z*M*N.
// ---------------------------------------------------------------------------
template <int TM>
__global__ __launch_bounds__(256) void k_gemm(const float* __restrict__ A,
                                              const float* __restrict__ Bm,
                                              float* __restrict__ Cm,
                                              int M, int N_, int ldA, int k_len)
{
    constexpr int W = TM / 16;  // micro rows per thread (4 or 2)
    __shared__ float As[16][TM];   // [kk][m]
    __shared__ float Bs[16][64];   // [kk][n]
    const int t = threadIdx.x;
    const int tx = t & 15;
    const int ty = t >> 4;
    const int bm = blockIdx.x * TM;
    const int bn = blockIdx.y * 64;
    const int kbase = blockIdx.z * k_len;
    Cm += (size_t)blockIdx.z * M * N_;

    float acc[W][4];
#pragma unroll
    for (int i = 0; i < W; ++i)
#pragma unroll
        for (int j = 0; j < 4; ++j) acc[i][j] = 0.f;

    for (int k0 = kbase; k0 < kbase + k_len; k0 += 16) {
        // ---- stage A tile (TM x 16), transposed into As[kk][m]
        if constexpr (W == 4) {
            int m = t >> 2;              // 0..63
            int kk = (t & 3) << 2;       // 0,4,8,12
            float4 av = *(const float4*)(A + (size_t)(bm + m) * ldA + k0 + kk);
            As[kk + 0][m] = av.x; As[kk + 1][m] = av.y;
            As[kk + 2][m] = av.z; As[kk + 3][m] = av.w;
        } else {
            int m = t >> 3;              // 0..31
            int kk = (t & 7) << 1;       // 0,2,...,14
            float2 av = *(const float2*)(A + (size_t)(bm + m) * ldA + k0 + kk);
            As[kk + 0][m] = av.x; As[kk + 1][m] = av.y;
        }
        // ---- stage B tile (16 x 64) with n-boundary guard (N_=200)
        {
            int kk = t >> 4;             // 0..15
            int n = (t & 15) << 2;       // 0..60
            const float* bp = Bm + (size_t)(k0 + kk) * N_ + bn + n;
            float4 bv;
            if (bn + n + 3 < N_) {
                bv = *(const float4*)bp;
            } else {
                bv.x = (bn + n + 0 < N_) ? bp[0] : 0.f;
                bv.y = (bn + n + 1 < N_) ? bp[1] : 0.f;
                bv.z = (bn + n + 2 < N_) ? bp[2] : 0.f;
                bv.w = (bn + n + 3 < N_) ? bp[3] : 0.f;
            }
            *(float4*)&Bs[kk][n] = bv;
        }
        __syncthreads();
#pragma unroll
        for (int kk = 0; kk < 16; ++kk) {
            float av[W];
            if constexpr (W == 4) {
                float4 a4 = *(const float4*)&As[kk][ty * 4];
                av[0] = a4.x; av[1] = a4.y; av[2] = a4.z; av[3] = a4.w;
            } else {
                float2 a2 = *(const float2*)&As[kk][ty * 2];
                av[0] = a2.x; av[1] = a2.y;
            }
            float4 b4 = *(const float4*)&Bs[kk][tx * 4];
            float bv4[4] = {b4.x, b4.y, b4.z, b4.w};
#pragma unroll
            for (int i = 0; i < W; ++i)
#pragma unroll
                for (int j = 0; j < 4; ++j)
                    acc[i][j] = fmaf(av[i], bv4[j], acc[i][j]);
        }
        __syncthreads();
    }
#pragma unroll
    for (int i = 0; i < W; ++i) {
        int m = bm + ty * W + i;
#pragma unroll
        for (int j = 0; j < 4; ++j) {
            int n = bn + tx * 4 + j;
            if (n < N_) Cm[(size_t)m * N_ + n] = acc[i][j];
        }
    }
}

// ---------------------------------------------------------------------------
// out[b,c] = (1/6) * sum_z part[z][b,c] + bvec[c]
// ---------------------------------------------------------------------------
__global__ __launch_bounds__(256) void k_combine(const float* __restrict__ part,
                                                 const float* __restrict__ bvec,
                                                 float* __restrict__ out)
{
    int idx = blockIdx.x * blockDim.x + threadIdx.x;
    if (idx >= NB * CC) return;
    int c = idx % CC;
    float acc = part[idx] + part[NB * CC + idx] + part[2 * NB * CC + idx] +
                part[3 * NB * CC + idx];
    out[idx] = acc * (1.f / 6.f) + bvec[c];
}

// ---------------------------------------------------------------------------
extern "C" void kernel_launch(void* const* d_in, const int* in_sizes, int n_in,
                              void* d_out, int out_size, void* d_ws, size_t ws_size,
                              hipStream_t stream)
{
    const float* part_feats = (const float*)d_in[0];
    const float* cdds = (const float*)d_in[1];
    const float* fc_w = (const float*)d_in[2];   // (4096, 1024)
    const float* fc_b = (const float*)d_in[3];   // (1024,)
    const float* cls_w = (const float*)d_in[4];  // (1024, 200)
    const float* cls_b = (const float*)d_in[5];  // (200,)
    float* out = (float*)d_out;                  // (2048, 200)

    char* ws = (char*)d_ws;
    size_t off = 0;
    float* pq = (float*)(ws + off);   off += (size_t)NB * K2 * 4;        // 33.5 MB
    float* Mbuf = (float*)(ws + off); off += (size_t)K2 * CC * 4;        // 3.3 MB
    float* part = (float*)(ws + off); off += (size_t)SPLITK * NB * CC * 4; // 6.6 MB
    float* sbuf = (float*)(ws + off); off += (size_t)NB * NNODE * 4;
    float* bvec = (float*)(ws + off); off += 256 * 4;

    // 1. graph weights s[b,u]
    k_s<<<dim3(NB / 256), dim3(256), 0, stream>>>(cdds, sbuf);
    // 2. bias vector
    k_bvec<<<dim3(CC / 8), dim3(256), 0, stream>>>(fc_b, cls_w, cls_b, bvec);
    // 3. pq = [weighted-sum, sum] over nodes  (streams part_feats once)
    k_pq<<<dim3(NB * (DD / 4) / 256), dim3(256), 0, stream>>>(part_feats, sbuf, pq);
    // 4. M = fc_w @ cls_w : (4096 x 200), K=1024, full-K (z=0)
    k_gemm<32><<<dim3(K2 / 32, (CC + 63) / 64, 1), dim3(256), 0, stream>>>(
        fc_w, cls_w, Mbuf, K2, CC, HH, HH);
    // 5. partials of pq @ M : (2048 x 200), K=4096 split 4 ways
    k_gemm<32><<<dim3(NB / 32, (CC + 63) / 64, SPLITK), dim3(256), 0, stream>>>(
        pq, Mbuf, part, NB, CC, K2, K2 / SPLITK);
    // 6. combine partials, scale by 1/N, add bias
    k_combine<<<dim3((NB * CC + 255) / 256), dim3(256), 0, stream>>>(part, bvec, out);
}

// Round 2
// 105.221 us; speedup vs baseline: 1.9661x; 1.9661x over previous
//
#include <hip/hip_runtime.h>
#include <math.h>

namespace {
constexpr int NB = 2048;      // batch
constexpr int NNODE = 6;      // nodes
constexpr int DD = 2048;      // feature dim
constexpr int HH = 1024;      // hidden
constexpr int CC = 200;       // classes
constexpr int K2 = 2 * DD;    // 4096 (concat dim)
constexpr int NPAD = 256;     // padded class dim (multiple of 64)
constexpr float ALPHA_C = 0.015f;
constexpr float SCALE_C = 24.0f;
}

typedef __attribute__((ext_vector_type(8))) short bf16x8;
typedef __attribute__((ext_vector_type(4))) float f32x4;

static __device__ __forceinline__ unsigned short f2bf(float x) {
    union { float f; unsigned int u; } v; v.f = x;
    unsigned int r = v.u + 0x7FFFu + ((v.u >> 16) & 1u);  // RNE
    return (unsigned short)(r >> 16);
}

// ---------------------------------------------------------------------------
// Convert fc_w (4096x1024 f32 -> bf16 same layout) and
// cls_w (1024x200 f32 -> cls_wT bf16 [256][1024], transposed, zero-padded).
// ---------------------------------------------------------------------------
__global__ __launch_bounds__(256) void k_cvt(const float* __restrict__ fc_w,
                                             const float* __restrict__ cls_w,
                                             unsigned short* __restrict__ fc_wB,
                                             unsigned short* __restrict__ cls_wT)
{
    int bid = blockIdx.x;
    int t = threadIdx.x;
    if (bid < 2048) {
        size_t i = ((size_t)bid * 256 + t) * 8;   // 8 floats per thread
        float4 a = *(const float4*)(fc_w + i);
        float4 b = *(const float4*)(fc_w + i + 4);
        uint4 o;
        o.x = (unsigned)f2bf(a.x) | ((unsigned)f2bf(a.y) << 16);
        o.y = (unsigned)f2bf(a.z) | ((unsigned)f2bf(a.w) << 16);
        o.z = (unsigned)f2bf(b.x) | ((unsigned)f2bf(b.y) << 16);
        o.w = (unsigned)f2bf(b.z) | ((unsigned)f2bf(b.w) << 16);
        *(uint4*)(fc_wB + i) = o;
    } else {
        int j = (bid - 2048) * 256 + t;           // 65536 threads, 4 elems each
        int e0 = j << 2;                          // linear index into [256][1024]
        int n = e0 >> 10;
        int k0 = e0 & 1023;
        ushort4 o;
        float v0 = (n < CC) ? cls_w[(size_t)(k0 + 0) * CC + n] : 0.f;
        float v1 = (n < CC) ? cls_w[(size_t)(k0 + 1) * CC + n] : 0.f;
        float v2 = (n < CC) ? cls_w[(size_t)(k0 + 2) * CC + n] : 0.f;
        float v3 = (n < CC) ? cls_w[(size_t)(k0 + 3) * CC + n] : 0.f;
        o.x = f2bf(v0); o.y = f2bf(v1); o.z = f2bf(v2); o.w = f2bf(v3);
        *(ushort4*)(cls_wT + (size_t)n * HH + k0) = o;
    }
}

// ---------------------------------------------------------------------------
// bvec[c] = sum_h fc_b[h]*cls_w[h,c] + cls_b[c]
// ---------------------------------------------------------------------------
__global__ __launch_bounds__(256) void k_bvec(const float* __restrict__ fc_b,
                                              const float* __restrict__ cls_w,
                                              const float* __restrict__ cls_b,
                                              float* __restrict__ bvec)
{
    __shared__ float red[256];
    int t = threadIdx.x;
    int c8 = t & 7;
    int hs = t >> 3;
    int c = blockIdx.x * 8 + c8;
    float acc = 0.f;
    for (int h = hs; h < HH; h += 32)
        acc += fc_b[h] * cls_w[h * CC + c];
    red[t] = acc;
    __syncthreads();
    for (int sft = 128; sft >= 8; sft >>= 1) {
        if (t < sft) red[t] += red[t + sft];
        __syncthreads();
    }
    if (t < 8) bvec[c] = red[t] + cls_b[c];
}

// ---------------------------------------------------------------------------
// Fused s + pq: pq[b][0:D] = sum_u s[b,u]*pf[b,u,:], pq[b][D:2D] = sum_u pf
// Output bf16. grid = NB*2 blocks x 256 threads (4 floats/thread).
// ---------------------------------------------------------------------------
__global__ __launch_bounds__(256) void k_pq(const float* __restrict__ pf,
                                            const float* __restrict__ cdds,
                                            unsigned short* __restrict__ pq)
{
    int bid = blockIdx.x;
    int b = bid >> 1;
    int d = ((bid & 1) << 10) + (threadIdx.x << 2);

    // --- node weights s[u] (redundant per thread; trivial vs memory stream)
    const float* cd = cdds + (size_t)b * NNODE * 6;
    float cx[NNODE], cy[NNODE];
#pragma unroll
    for (int u = 0; u < NNODE; ++u) {
        cy[u] = (cd[u * 6 + 1] + cd[u * 6 + 3]) * 0.5f;
        cx[u] = (cd[u * 6 + 2] + cd[u * 6 + 4]) * 0.5f;
    }
    float w0[NNODE][NNODE];
    float sum = 0.f;
#pragma unroll
    for (int u = 0; u < NNODE; ++u)
#pragma unroll
        for (int v = 0; v < NNODE; ++v) {
            if (v == u) { w0[u][v] = 0.f; continue; }
            float dx = cx[u] - cx[v];
            float dy = cy[u] - cy[v];
            float w = expf(-ALPHA_C * sqrtf(dx * dx + dy * dy));
            w0[u][v] = w;
            sum += w;
        }
    float mean = sum * (1.f / 30.f);
    float sv[NNODE];
#pragma unroll
    for (int u = 0; u < NNODE; ++u) {
        float acc = 0.f;
#pragma unroll
        for (int v = 0; v < NNODE; ++v) {
            float tt = w0[u][v] - mean;
            if (v != u && tt > 0.f) acc += tt;
        }
        sv[u] = SCALE_C * acc * 0.2f;   // /(N-1)
    }

    // --- weighted & plain sums over the 6 nodes
    const float* base = pf + (size_t)b * NNODE * DD + d;
    float4 p = {0.f, 0.f, 0.f, 0.f};
    float4 q = {0.f, 0.f, 0.f, 0.f};
#pragma unroll
    for (int u = 0; u < NNODE; ++u) {
        float4 a = *(const float4*)(base + (size_t)u * DD);
        p.x = fmaf(sv[u], a.x, p.x); p.y = fmaf(sv[u], a.y, p.y);
        p.z = fmaf(sv[u], a.z, p.z); p.w = fmaf(sv[u], a.w, p.w);
        q.x += a.x; q.y += a.y; q.z += a.z; q.w += a.w;
    }
    unsigned short* o = pq + (size_t)b * K2;
    ushort4 pb, qb;
    pb.x = f2bf(p.x); pb.y = f2bf(p.y); pb.z = f2bf(p.z); pb.w = f2bf(p.w);
    qb.x = f2bf(q.x); qb.y = f2bf(q.y); qb.z = f2bf(q.z); qb.w = f2bf(q.w);
    *(ushort4*)(o + d) = pb;
    *(ushort4*)(o + DD + d) = qb;
}

// ---------------------------------------------------------------------------
// GEMM1: Mt[256][4096] = (fc_wB[4096][1024] @ cls_wT^T)^T  (bf16 MFMA)
// grid (64, 4); 64x64 tile; 4 waves of 32x32.
// ---------------------------------------------------------------------------
__global__ __launch_bounds__(256) void k_gemm1(const unsigned short* __restrict__ A,
                                               const unsigned short* __restrict__ Bt,
                                               unsigned short* __restrict__ Mt)
{
    __shared__ short As[64][72];   // +8 pad: row stride 144B = 4 banks mod 32
    __shared__ short Bs[64][72];
    const int t = threadIdx.x;
    const int lane = t & 63;
    const int wid = t >> 6;
    const int wm = wid >> 1, wn = wid & 1;
    const int bm = blockIdx.x * 64, bn = blockIdx.y * 64;

    f32x4 acc[2][2] = {};

    for (int k0 = 0; k0 < HH; k0 += 64) {
#pragma unroll
        for (int c = 0; c < 2; ++c) {
            int i = t + c * 256;
            int row = i >> 3, col8 = (i & 7) << 3;
            uint4 av = *(const uint4*)(A + (size_t)(bm + row) * HH + k0 + col8);
            *(uint4*)&As[row][col8] = av;
            uint4 bv = *(const uint4*)(Bt + (size_t)(bn + row) * HH + k0 + col8);
            *(uint4*)&Bs[row][col8] = bv;
        }
        __syncthreads();
#pragma unroll
        for (int ks = 0; ks < 2; ++ks) {
            int kk = ks * 32 + ((lane >> 4) << 3);
            bf16x8 a0 = *(const bf16x8*)&As[wm * 32 + (lane & 15)][kk];
            bf16x8 a1 = *(const bf16x8*)&As[wm * 32 + 16 + (lane & 15)][kk];
            bf16x8 b0 = *(const bf16x8*)&Bs[wn * 32 + (lane & 15)][kk];
            bf16x8 b1 = *(const bf16x8*)&Bs[wn * 32 + 16 + (lane & 15)][kk];
            acc[0][0] = __builtin_amdgcn_mfma_f32_16x16x32_bf16(a0, b0, acc[0][0], 0, 0, 0);
            acc[0][1] = __builtin_amdgcn_mfma_f32_16x16x32_bf16(a0, b1, acc[0][1], 0, 0, 0);
            acc[1][0] = __builtin_amdgcn_mfma_f32_16x16x32_bf16(a1, b0, acc[1][0], 0, 0, 0);
            acc[1][1] = __builtin_amdgcn_mfma_f32_16x16x32_bf16(a1, b1, acc[1][1], 0, 0, 0);
        }
        __syncthreads();
    }
    // C/D layout: col = lane&15, row = (lane>>4)*4 + reg  -> transposed store
#pragma unroll
    for (int fm = 0; fm < 2; ++fm)
#pragma unroll
        for (int fn = 0; fn < 2; ++fn) {
            int gm0 = bm + wm * 32 + fm * 16 + ((lane >> 4) << 2);
            int gn = bn + wn * 32 + fn * 16 + (lane & 15);
            ushort4 o;
            o.x = f2bf(acc[fm][fn][0]); o.y = f2bf(acc[fm][fn][1]);
            o.z = f2bf(acc[fm][fn][2]); o.w = f2bf(acc[fm][fn][3]);
            *(ushort4*)(Mt + (size_t)gn * K2 + gm0) = o;
        }
}

// ---------------------------------------------------------------------------
// GEMM2: part[z][2048][200] = pq[2048][4096] @ Mt^T  (bf16 MFMA, split-K=2)
// grid (32, 4, 2); 64x64 tile; 4 waves of 32x32.
// ---------------------------------------------------------------------------
__global__ __launch_bounds__(256) void k_gemm2(const unsigned short* __restrict__ A,
                                               const unsigned short* __restrict__ Bt,
                                               float* __restrict__ part)
{
    __shared__ short As[64][72];
    __shared__ short Bs[64][72];
    const int t = threadIdx.x;
    const int lane = t & 63;
    const int wid = t >> 6;
    const int wm = wid >> 1, wn = wid & 1;
    const int bm = blockIdx.x * 64, bn = blockIdx.y * 64;
    const int z = blockIdx.z;
    const int kbase = z * (K2 / 2);

    f32x4 acc[2][2] = {};

    for (int k0 = kbase; k0 < kbase + K2 / 2; k0 += 64) {
#pragma unroll
        for (int c = 0; c < 2; ++c) {
            int i = t + c * 256;
            int row = i >> 3, col8 = (i & 7) << 3;
            uint4 av = *(const uint4*)(A + (size_t)(bm + row) * K2 + k0 + col8);
            *(uint4*)&As[row][col8] = av;
            uint4 bv = *(const uint4*)(Bt + (size_t)(bn + row) * K2 + k0 + col8);
            *(uint4*)&Bs[row][col8] = bv;
        }
        __syncthreads();
#pragma unroll
        for (int ks = 0; ks < 2; ++ks) {
            int kk = ks * 32 + ((lane >> 4) << 3);
            bf16x8 a0 = *(const bf16x8*)&As[wm * 32 + (lane & 15)][kk];
            bf16x8 a1 = *(const bf16x8*)&As[wm * 32 + 16 + (lane & 15)][kk];
            bf16x8 b0 = *(const bf16x8*)&Bs[wn * 32 + (lane & 15)][kk];
            bf16x8 b1 = *(const bf16x8*)&Bs[wn * 32 + 16 + (lane & 15)][kk];
            acc[0][0] = __builtin_amdgcn_mfma_f32_16x16x32_bf16(a0, b0, acc[0][0], 0, 0, 0);
            acc[0][1] = __builtin_amdgcn_mfma_f32_16x16x32_bf16(a0, b1, acc[0][1], 0, 0, 0);
            acc[1][0] = __builtin_amdgcn_mfma_f32_16x16x32_bf16(a1, b0, acc[1][0], 0, 0, 0);
            acc[1][1] = __builtin_amdgcn_mfma_f32_16x16x32_bf16(a1, b1, acc[1][1], 0, 0, 0);
        }
        __syncthreads();
    }
#pragma unroll
    for (int fm = 0; fm < 2; ++fm)
#pragma unroll
        for (int fn = 0; fn < 2; ++fn) {
            int gm0 = bm + wm * 32 + fm * 16 + ((lane >> 4) << 2);
            int gn = bn + wn * 32 + fn * 16 + (lane & 15);
            if (gn < CC) {
#pragma unroll
                for (int r = 0; r < 4; ++r)
                    part[((size_t)z * NB + gm0 + r) * CC + gn] = acc[fm][fn][r];
            }
        }
}

// ---------------------------------------------------------------------------
// out[b,c] = (part0 + part1)/6 + bvec[c]
// ---------------------------------------------------------------------------
__global__ __launch_bounds__(256) void k_combine(const float* __restrict__ part,
                                                 const float* __restrict__ bvec,
                                                 float* __restrict__ out)
{
    int idx = blockIdx.x * blockDim.x + threadIdx.x;
    if (idx >= NB * CC) return;
    int c = idx - (idx / CC) * CC;
    out[idx] = (part[idx] + part[(size_t)NB * CC + idx]) * (1.f / 6.f) + bvec[c];
}

// ---------------------------------------------------------------------------
extern "C" void kernel_launch(void* const* d_in, const int* in_sizes, int n_in,
                              void* d_out, int out_size, void* d_ws, size_t ws_size,
                              hipStream_t stream)
{
    const float* part_feats = (const float*)d_in[0];
    const float* cdds = (const float*)d_in[1];
    const float* fc_w = (const float*)d_in[2];   // (4096, 1024)
    const float* fc_b = (const float*)d_in[3];   // (1024,)
    const float* cls_w = (const float*)d_in[4];  // (1024, 200)
    const float* cls_b = (const float*)d_in[5];  // (200,)
    float* out = (float*)d_out;                  // (2048, 200)

    char* ws = (char*)d_ws;
    size_t off = 0;
    unsigned short* pq = (unsigned short*)(ws + off);     off += (size_t)NB * K2 * 2;      // 16.8 MB
    unsigned short* fc_wB = (unsigned short*)(ws + off);  off += (size_t)K2 * HH * 2;      // 8.4 MB
    unsigned short* cls_wT = (unsigned short*)(ws + off); off += (size_t)NPAD * HH * 2;    // 0.5 MB
    unsigned short* Mt = (unsigned short*)(ws + off);     off += (size_t)NPAD * K2 * 2;    // 2.1 MB
    float* part = (float*)(ws + off);                     off += (size_t)2 * NB * CC * 4;  // 3.3 MB
    float* bvec = (float*)(ws + off);                     off += 256 * 4;

    // 1. weight conversion (fc_w -> bf16; cls_w -> transposed padded bf16)
    k_cvt<<<dim3(2048 + NPAD), dim3(256), 0, stream>>>(fc_w, cls_w, fc_wB, cls_wT);
    // 2. bias vector
    k_bvec<<<dim3(CC / 8), dim3(256), 0, stream>>>(fc_b, cls_w, cls_b, bvec);
    // 3. Mt = (fc_w @ cls_w)^T  bf16, padded
    k_gemm1<<<dim3(K2 / 64, NPAD / 64), dim3(256), 0, stream>>>(fc_wB, cls_wT, Mt);
    // 4. pq = [weighted-sum | sum] over nodes, bf16 (fused node-weight calc)
    k_pq<<<dim3(NB * 2), dim3(256), 0, stream>>>(part_feats, cdds, pq);
    // 5. pq @ M partials (split-K=2)
    k_gemm2<<<dim3(NB / 64, NPAD / 64, 2), dim3(256), 0, stream>>>(pq, Mt, part);
    // 6. combine + scale + bias
    k_combine<<<dim3((NB * CC + 255) / 256), dim3(256), 0, stream>>>(part, bvec, out);
}